// Round 6
// baseline (15934.605 us; speedup 1.0000x reference)
//
#include <hip/hip_runtime.h>

#define TMQ 32          // row tile
#define LDS_STRIDE 132  // 128 + 4 pad
#define BN_EPS 1e-5f
#define SCAN_CHUNK 1024 // elements per scan block (256 thr x 4)

// ---------------------------------------------------------------- ea MLP + folded Q/K biases
__global__ __launch_bounds__(128) void k_ea(
    const float* __restrict__ nt, const float* __restrict__ et,
    const float* __restrict__ mW1, const float* __restrict__ mb1,
    const float* __restrict__ m_g, const float* __restrict__ m_b,
    const float* __restrict__ m_m, const float* __restrict__ m_v,
    const float* __restrict__ mW2, const float* __restrict__ mb2,
    const float* __restrict__ qW, const float* __restrict__ qb,
    const float* __restrict__ kW, const float* __restrict__ kb,
    float* __restrict__ eaq, float* __restrict__ eak)
{
    __shared__ float merged[256];
    __shared__ float h[128];
    __shared__ float sea[128];
    const int t = threadIdx.x;
    merged[t]       = nt[t];
    merged[128 + t] = et[t];
    __syncthreads();
    float acc = mb1[t];
    for (int i = 0; i < 256; ++i) acc = fmaf(merged[i], mW1[i * 128 + t], acc);
    acc = (acc - m_m[t]) * rsqrtf(m_v[t] + BN_EPS) * m_g[t] + m_b[t];
    h[t] = acc > 0.f ? acc : 0.f;
    __syncthreads();
    float acc2 = mb2[t];
    for (int k = 0; k < 128; ++k) acc2 = fmaf(h[k], mW2[k * 128 + t], acc2);
    sea[t] = acc2;
    __syncthreads();
    float aq = qb[t], ak = kb[t];
    for (int k = 0; k < 128; ++k) {
        const float e = sea[k];
        aq = fmaf(e, qW[k * 128 + t], aq);
        ak = fmaf(e, kW[k * 128 + t], ak);
    }
    eaq[t] = aq;
    eak[t] = ak;
}

// ---------------------------------------------------------------- 2-row GEMM, hand-pipelined
// acc[i][j] += sum_k T[i0+i][k] * W[k][j0+j]. Two named register buffers (A,B)
// alternate: while FMAs consume one k4-block (4 k-rows, 8 cols), the loads for
// the next k4-block are in flight. All guards compile-time (full unroll).
#define LOAD_WB(BUF, K4)                                                  \
    {                                                                     \
        const float* wr_ = W + (size_t)((K4) * 4) * 128 + j0;             \
        BUF[0] = *(const float4*)(wr_);                                   \
        BUF[1] = *(const float4*)(wr_ + 4);                               \
        BUF[2] = *(const float4*)(wr_ + 128);                             \
        BUF[3] = *(const float4*)(wr_ + 132);                             \
        BUF[4] = *(const float4*)(wr_ + 256);                             \
        BUF[5] = *(const float4*)(wr_ + 260);                             \
        BUF[6] = *(const float4*)(wr_ + 384);                             \
        BUF[7] = *(const float4*)(wr_ + 388);                             \
    }

#define FMA_WB(BUF, K4)                                                   \
    {                                                                     \
        const float4 x0_ = *(const float4*)(T + i0 * LDS_STRIDE + (K4) * 4);       \
        const float4 x1_ = *(const float4*)(T + (i0 + 1) * LDS_STRIDE + (K4) * 4); \
        _Pragma("unroll")                                                 \
        for (int kk = 0; kk < 4; ++kk) {                                  \
            const float4 w0 = BUF[2 * kk];                                \
            const float4 w1 = BUF[2 * kk + 1];                            \
            const float a0 = ((const float*)&x0_)[kk];                    \
            const float a1 = ((const float*)&x1_)[kk];                    \
            acc[0][0] = fmaf(a0, w0.x, acc[0][0]); acc[0][1] = fmaf(a0, w0.y, acc[0][1]); \
            acc[0][2] = fmaf(a0, w0.z, acc[0][2]); acc[0][3] = fmaf(a0, w0.w, acc[0][3]); \
            acc[0][4] = fmaf(a0, w1.x, acc[0][4]); acc[0][5] = fmaf(a0, w1.y, acc[0][5]); \
            acc[0][6] = fmaf(a0, w1.z, acc[0][6]); acc[0][7] = fmaf(a0, w1.w, acc[0][7]); \
            acc[1][0] = fmaf(a1, w0.x, acc[1][0]); acc[1][1] = fmaf(a1, w0.y, acc[1][1]); \
            acc[1][2] = fmaf(a1, w0.z, acc[1][2]); acc[1][3] = fmaf(a1, w0.w, acc[1][3]); \
            acc[1][4] = fmaf(a1, w1.x, acc[1][4]); acc[1][5] = fmaf(a1, w1.y, acc[1][5]); \
            acc[1][6] = fmaf(a1, w1.z, acc[1][6]); acc[1][7] = fmaf(a1, w1.w, acc[1][7]); \
        }                                                                 \
    }

__device__ __forceinline__ void tile_gemm2_pf(const float* __restrict__ T,
                                              const float* __restrict__ W,
                                              int i0, int j0, float acc[2][8])
{
    float4 A[8], B[8];
    LOAD_WB(A, 0)
#pragma unroll
    for (int k4 = 0; k4 < 32; k4 += 2) {
        if (k4 + 1 < 32) LOAD_WB(B, k4 + 1)
        FMA_WB(A, k4)
        if (k4 + 2 < 32) LOAD_WB(A, k4 + 2)
        if (k4 + 1 < 32) FMA_WB(B, k4 + 1)
    }
}

// ---------------------------------------------------------------- Q/K/V: one pass per blockIdx.y
__global__ __launch_bounds__(256, 4) void k_qkv(
    const float* __restrict__ x,
    const float* __restrict__ qW, const float* __restrict__ eaq,
    const float* __restrict__ kW, const float* __restrict__ eak,
    const float* __restrict__ vW, const float* __restrict__ vb,
    float* __restrict__ Q, float* __restrict__ K, float* __restrict__ V, int N)
{
    __shared__ float sx[TMQ * LDS_STRIDE];
    const int tid = threadIdx.x;
    const int n0 = blockIdx.x * TMQ;
    const int w  = blockIdx.y;
#pragma unroll
    for (int r = 0; r < 4; ++r) {
        const int flat = (r * 256 + tid) * 4;
        const int i = flat >> 7, c = flat & 127;
        const int n = n0 + i;
        float4 xv = make_float4(0.f, 0.f, 0.f, 0.f);
        if (n < N) xv = *(const float4*)(x + (size_t)n * 128 + c);
        float* pt = sx + i * LDS_STRIDE + c;
        pt[0] = xv.x; pt[1] = xv.y; pt[2] = xv.z; pt[3] = xv.w;
    }
    __syncthreads();
    const int tj = tid & 15, ti = tid >> 4;
    const int j0 = tj * 8, i0 = ti * 2;

    const float* W  = (w == 0) ? qW  : (w == 1) ? kW  : vW;
    const float* bi = (w == 0) ? eaq : (w == 1) ? eak : vb;  // eaq/eak fold ea-term + bias
    float* O        = (w == 0) ? Q   : (w == 1) ? K   : V;
    const float scale = (w == 0) ? 0.25f : 1.0f;             // q = (..)/sqrt(16)

    float acc[2][8] = {};
    tile_gemm2_pf(sx, W, i0, j0, acc);

    const float4 b0 = *(const float4*)(bi + j0);
    const float4 b1 = *(const float4*)(bi + j0 + 4);
#pragma unroll
    for (int i = 0; i < 2; ++i) {
        const int n = n0 + i0 + i;
        if (n >= N) continue;
        float4 o0, o1;
        o0.x = (acc[i][0] + b0.x) * scale; o0.y = (acc[i][1] + b0.y) * scale;
        o0.z = (acc[i][2] + b0.z) * scale; o0.w = (acc[i][3] + b0.w) * scale;
        o1.x = (acc[i][4] + b1.x) * scale; o1.y = (acc[i][5] + b1.y) * scale;
        o1.z = (acc[i][6] + b1.z) * scale; o1.w = (acc[i][7] + b1.w) * scale;
        *(float4*)(O + (size_t)n * 128 + j0)     = o0;
        *(float4*)(O + (size_t)n * 128 + j0 + 4) = o1;
    }
}

// ---------------------------------------------------------------- edge pass 1: ex + ssum
__global__ __launch_bounds__(256) void k_edge1(
    const int* __restrict__ ei, const float* __restrict__ Q,
    const float* __restrict__ K, float* __restrict__ ex,
    float* __restrict__ ssum, int E)
{
    const int t = blockIdx.x * 256 + threadIdx.x;   // one (edge, head) per thread
    const int e = t >> 3;
    if (e >= E) return;
    const int h = t & 7;
    const int s = ei[e];
    const int d = ei[E + e];
    const float* qp = Q + (size_t)s * 128 + h * 16;
    const float* kp = K + (size_t)d * 128 + h * 16;
    float acc = 0.f;
#pragma unroll
    for (int r = 0; r < 4; ++r) {
        const float4 a = *(const float4*)(qp + r * 4);
        const float4 b = *(const float4*)(kp + r * 4);
        acc += a.x * b.x + a.y * b.y + a.z * b.z + a.w * b.w;
    }
    const float v = __expf(acc);   // |score| small; no max-subtraction needed
    ex[(size_t)e * 8 + h] = v;
    unsafeAtomicAdd(&ssum[(size_t)s * 8 + h], v);
}

// ---------------------------------------------------------------- CSR build (dst)
__global__ __launch_bounds__(256) void k_hist(const int* __restrict__ ei,
                                              int* __restrict__ deg, int E)
{
    const int e = blockIdx.x * 256 + threadIdx.x;
    if (e < E) atomicAdd(&deg[ei[E + e]], 1);
}

__global__ __launch_bounds__(256) void k_scan_partial(const int* __restrict__ deg,
                                                      int* __restrict__ part, int N)
{
    __shared__ int sd[256];
    const int b = blockIdx.x, t = threadIdx.x;
    const int base = b * SCAN_CHUNK + t * 4;
    int s = 0;
#pragma unroll
    for (int i = 0; i < 4; ++i) { const int idx = base + i; if (idx < N) s += deg[idx]; }
    sd[t] = s; __syncthreads();
    for (int off = 128; off > 0; off >>= 1) {
        if (t < off) sd[t] += sd[t + off];
        __syncthreads();
    }
    if (t == 0) part[b] = sd[0];
}

__global__ __launch_bounds__(256) void k_scan_top(int* __restrict__ part, int nb)
{
    __shared__ int sd[256];
    const int t = threadIdx.x;
    const int orig = (t < nb) ? part[t] : 0;
    sd[t] = orig;
    __syncthreads();
    for (int off = 1; off < 256; off <<= 1) {
        const int v = (t >= off) ? sd[t - off] : 0;
        __syncthreads();
        sd[t] += v;
        __syncthreads();
    }
    if (t < nb) part[t] = sd[t] - orig;   // exclusive
}

__global__ __launch_bounds__(256) void k_scan_final(const int* __restrict__ deg,
                                                    const int* __restrict__ part,
                                                    int* __restrict__ row_start,
                                                    int* __restrict__ cursor, int N)
{
    __shared__ int ts[256];
    const int b = blockIdx.x, t = threadIdx.x;
    const int base = b * SCAN_CHUNK + t * 4;
    int v[4]; int s = 0;
#pragma unroll
    for (int i = 0; i < 4; ++i) { const int idx = base + i; v[i] = (idx < N) ? deg[idx] : 0; s += v[i]; }
    ts[t] = s; __syncthreads();
    for (int off = 1; off < 256; off <<= 1) {
        const int vv = (t >= off) ? ts[t - off] : 0;
        __syncthreads();
        ts[t] += vv;
        __syncthreads();
    }
    int run = part[b] + ((t > 0) ? ts[t - 1] : 0);
#pragma unroll
    for (int i = 0; i < 4; ++i) {
        const int idx = base + i;
        if (idx < N) { row_start[idx] = run; cursor[idx] = run; run += v[i]; }
    }
}

__global__ __launch_bounds__(256) void k_scatter(const int* __restrict__ ei,
                                                 int* __restrict__ cursor,
                                                 int* __restrict__ elist, int E)
{
    const int e = blockIdx.x * 256 + threadIdx.x;
    if (e < E) {
        const int pos = atomicAdd(&cursor[ei[E + e]], 1);
        elist[pos] = e;
    }
}

// ---------------------------------------------------------------- aggregation: 1 wave / dst node
__global__ __launch_bounds__(256) void k_aggr(
    const int* __restrict__ ei, const int* __restrict__ elist,
    const int* __restrict__ row_start, const int* __restrict__ deg,
    const float* __restrict__ V, const float* __restrict__ ex,
    const float* __restrict__ ssum, float* __restrict__ aggr, int N, int E)
{
    const int tid = threadIdx.x;
    const int n = blockIdx.x * 4 + (tid >> 6);
    if (n >= N) return;
    const int lane = tid & 63;
    const int h = lane >> 3;
    const int rs = row_start[n];
    const int dg = deg[n];
    float2 acc = make_float2(0.f, 0.f);
    for (int j = 0; j < dg; ++j) {
        const int e = elist[rs + j];
        const int s = ei[e];
        const float a = ex[(size_t)e * 8 + h] / ssum[(size_t)s * 8 + h];
        const float2 v = *(const float2*)(V + (size_t)s * 128 + lane * 2);
        acc.x = fmaf(v.x, a, acc.x);
        acc.y = fmaf(v.y, a, acc.y);
    }
    *(float2*)(aggr + (size_t)n * 128 + lane * 2) = acc;
}

// ---------------------------------------------------------------- fused residual + out MLP
__global__ __launch_bounds__(256, 4) void k_out(
    const float* __restrict__ x, const float* __restrict__ aggr,
    const float* __restrict__ resW,
    const float* __restrict__ oW1, const float* __restrict__ ob1,
    const float* __restrict__ o_g, const float* __restrict__ o_b,
    const float* __restrict__ o_m, const float* __restrict__ o_v,
    const float* __restrict__ oW2, const float* __restrict__ ob2,
    float* __restrict__ out, int N)
{
    __shared__ float sa[TMQ * LDS_STRIDE];
    const int tid = threadIdx.x;
    const int n0 = blockIdx.x * TMQ;
#pragma unroll
    for (int r = 0; r < 4; ++r) {
        const int flat = (r * 256 + tid) * 4;
        const int i = flat >> 7, c = flat & 127;
        const int n = n0 + i;
        float4 xv = make_float4(0.f, 0.f, 0.f, 0.f);
        if (n < N) xv = *(const float4*)(x + (size_t)n * 128 + c);
        float* p = sa + i * LDS_STRIDE + c;
        p[0] = xv.x; p[1] = xv.y; p[2] = xv.z; p[3] = xv.w;
    }
    __syncthreads();
    const int tj = tid & 15, ti = tid >> 4;
    const int j0 = tj * 8, i0 = ti * 2;

    // stage 1: z = x @ resW + aggr (z in registers across the sync)
    {
        float acc[2][8] = {};
        tile_gemm2_pf(sa, resW, i0, j0, acc);
#pragma unroll
        for (int i = 0; i < 2; ++i) {
            const int n = n0 + i0 + i;
            float4 a0 = make_float4(0.f, 0.f, 0.f, 0.f), a1 = a0;
            if (n < N) {
                a0 = *(const float4*)(aggr + (size_t)n * 128 + j0);
                a1 = *(const float4*)(aggr + (size_t)n * 128 + j0 + 4);
            }
            acc[i][0] += a0.x; acc[i][1] += a0.y; acc[i][2] += a0.z; acc[i][3] += a0.w;
            acc[i][4] += a1.x; acc[i][5] += a1.y; acc[i][6] += a1.z; acc[i][7] += a1.w;
        }
        __syncthreads();
#pragma unroll
        for (int i = 0; i < 2; ++i) {
            float* p = sa + (i0 + i) * LDS_STRIDE + j0;
#pragma unroll
            for (int j = 0; j < 8; ++j) p[j] = acc[i][j];
        }
    }
    __syncthreads();

    // stage 2: t = leaky_relu(bn(z @ oW1 + ob1))
    {
        float acc[2][8] = {};
        tile_gemm2_pf(sa, oW1, i0, j0, acc);
        const float4 bb0 = *(const float4*)(ob1 + j0), bb1 = *(const float4*)(ob1 + j0 + 4);
        const float4 mm0 = *(const float4*)(o_m + j0), mm1 = *(const float4*)(o_m + j0 + 4);
        const float4 vv0 = *(const float4*)(o_v + j0), vv1 = *(const float4*)(o_v + j0 + 4);
        const float4 gg0 = *(const float4*)(o_g + j0), gg1 = *(const float4*)(o_g + j0 + 4);
        const float4 oo0 = *(const float4*)(o_b + j0), oo1 = *(const float4*)(o_b + j0 + 4);
        float bbv[8] = {bb0.x, bb0.y, bb0.z, bb0.w, bb1.x, bb1.y, bb1.z, bb1.w};
        float mmv[8] = {mm0.x, mm0.y, mm0.z, mm0.w, mm1.x, mm1.y, mm1.z, mm1.w};
        float vvv[8] = {vv0.x, vv0.y, vv0.z, vv0.w, vv1.x, vv1.y, vv1.z, vv1.w};
        float ggv[8] = {gg0.x, gg0.y, gg0.z, gg0.w, gg1.x, gg1.y, gg1.z, gg1.w};
        float oov[8] = {oo0.x, oo0.y, oo0.z, oo0.w, oo1.x, oo1.y, oo1.z, oo1.w};
#pragma unroll
        for (int i = 0; i < 2; ++i)
#pragma unroll
            for (int j = 0; j < 8; ++j) {
                float u = acc[i][j] + bbv[j];
                u = (u - mmv[j]) * rsqrtf(vvv[j] + BN_EPS) * ggv[j] + oov[j];
                acc[i][j] = u > 0.f ? u : 0.01f * u;   // leaky_relu(0.01)
            }
        __syncthreads();
#pragma unroll
        for (int i = 0; i < 2; ++i) {
            float* p = sa + (i0 + i) * LDS_STRIDE + j0;
#pragma unroll
            for (int j = 0; j < 8; ++j) p[j] = acc[i][j];
        }
    }
    __syncthreads();

    // stage 3: out = t @ oW2 + ob2
    {
        float acc[2][8] = {};
        tile_gemm2_pf(sa, oW2, i0, j0, acc);
        const float4 b0 = *(const float4*)(ob2 + j0);
        const float4 b1 = *(const float4*)(ob2 + j0 + 4);
#pragma unroll
        for (int i = 0; i < 2; ++i) {
            const int n = n0 + i0 + i;
            if (n >= N) continue;
            float4 o0, o1;
            o0.x = acc[i][0] + b0.x; o0.y = acc[i][1] + b0.y;
            o0.z = acc[i][2] + b0.z; o0.w = acc[i][3] + b0.w;
            o1.x = acc[i][4] + b1.x; o1.y = acc[i][5] + b1.y;
            o1.z = acc[i][6] + b1.z; o1.w = acc[i][7] + b1.w;
            *(float4*)(out + (size_t)n * 128 + j0)     = o0;
            *(float4*)(out + (size_t)n * 128 + j0 + 4) = o1;
        }
    }
}

// ---------------------------------------------------------------- launch
extern "C" void kernel_launch(void* const* d_in, const int* in_sizes, int n_in,
                              void* d_out, int out_size, void* d_ws, size_t ws_size,
                              hipStream_t stream)
{
    const float* x    = (const float*)d_in[0];
    const int*   ei   = (const int*)d_in[1];
    const float* nt   = (const float*)d_in[2];
    const float* et   = (const float*)d_in[3];
    const float* mW1  = (const float*)d_in[4];
    const float* mb1  = (const float*)d_in[5];
    const float* m_g  = (const float*)d_in[6];
    const float* m_b  = (const float*)d_in[7];
    const float* m_m  = (const float*)d_in[8];
    const float* m_v  = (const float*)d_in[9];
    const float* mW2  = (const float*)d_in[10];
    const float* mb2  = (const float*)d_in[11];
    const float* resW = (const float*)d_in[12];
    const float* qW   = (const float*)d_in[13];
    const float* qb   = (const float*)d_in[14];
    const float* kW   = (const float*)d_in[15];
    const float* kb   = (const float*)d_in[16];
    const float* vW   = (const float*)d_in[17];
    const float* vb   = (const float*)d_in[18];
    const float* oW1  = (const float*)d_in[19];
    const float* ob1  = (const float*)d_in[20];
    const float* o_g  = (const float*)d_in[21];
    const float* o_b  = (const float*)d_in[22];
    const float* o_m  = (const float*)d_in[23];
    const float* o_v  = (const float*)d_in[24];
    const float* oW2  = (const float*)d_in[25];
    const float* ob2  = (const float*)d_in[26];
    float* out = (float*)d_out;

    const int N = in_sizes[0] / 128;
    const int E = in_sizes[1] / 2;

    // workspace layout (floats): eaq|eak | Q | K | V | ex | ssum | [ints] deg,row_start,cursor,part,elist
    float* ws   = (float*)d_ws;
    float* eaq  = ws;
    float* eak  = ws + 128;
    float* Q    = ws + 256;
    float* K    = Q + (size_t)N * 128;
    float* V    = K + (size_t)N * 128;
    float* ex   = V + (size_t)N * 128;
    float* ssum = ex + (size_t)E * 8;
    int* deg       = (int*)(ssum + (size_t)N * 8);
    int* row_start = deg + N;
    int* cursor    = row_start + N;
    int* part      = cursor + N;
    int* elist     = part + 256;
    float* aggr = Q;   // Q dead after edge pass 1

    const int nb   = (N + TMQ - 1) / TMQ;
    const int nbsc = (N + SCAN_CHUNK - 1) / SCAN_CHUNK;   // scan blocks (<=256)

    hipMemsetAsync(ssum, 0, (size_t)N * 8 * sizeof(float), stream);
    hipMemsetAsync(deg, 0, (size_t)N * sizeof(int), stream);

    k_ea<<<1, 128, 0, stream>>>(nt, et, mW1, mb1, m_g, m_b, m_m, m_v, mW2, mb2,
                                qW, qb, kW, kb, eaq, eak);
    k_qkv<<<dim3(nb, 3), 256, 0, stream>>>(x, qW, eaq, kW, eak, vW, vb, Q, K, V, N);

    // CSR build (independent of Q/K/V values)
    k_hist<<<(E + 255) / 256, 256, 0, stream>>>(ei, deg, E);
    k_scan_partial<<<nbsc, 256, 0, stream>>>(deg, part, N);
    k_scan_top<<<1, 256, 0, stream>>>(part, nbsc);
    k_scan_final<<<nbsc, 256, 0, stream>>>(deg, part, row_start, cursor, N);
    k_scatter<<<(E + 255) / 256, 256, 0, stream>>>(ei, cursor, elist, E);

    k_edge1<<<(int)(((size_t)E * 8 + 255) / 256), 256, 0, stream>>>(ei, Q, K, ex, ssum, E);
    k_aggr<<<(N + 3) / 4, 256, 0, stream>>>(ei, elist, row_start, deg, V, ex, ssum, aggr, N, E);
    k_out<<<nb, 256, 0, stream>>>(x, aggr, resW, oW1, ob1, o_g, o_b, o_m, o_v, oW2, ob2, out, N);
}

// Round 7
// 744.217 us; speedup vs baseline: 21.4112x; 21.4112x over previous
//
#include <hip/hip_runtime.h>

#define TM 64
#define LDS_STRIDE 132   // 128 + 4 pad
#define BN_EPS 1e-5f
#define SCAN_CHUNK 1024  // elements per scan block (256 thr x 4)

// ---------------------------------------------------------------- ea MLP + folded Q/K biases
__global__ __launch_bounds__(128) void k_ea(
    const float* __restrict__ nt, const float* __restrict__ et,
    const float* __restrict__ mW1, const float* __restrict__ mb1,
    const float* __restrict__ m_g, const float* __restrict__ m_b,
    const float* __restrict__ m_m, const float* __restrict__ m_v,
    const float* __restrict__ mW2, const float* __restrict__ mb2,
    const float* __restrict__ qW, const float* __restrict__ qb,
    const float* __restrict__ kW, const float* __restrict__ kb,
    float* __restrict__ eaq, float* __restrict__ eak)
{
    __shared__ float merged[256];
    __shared__ float h[128];
    __shared__ float sea[128];
    const int t = threadIdx.x;
    merged[t]       = nt[t];
    merged[128 + t] = et[t];
    __syncthreads();
    float acc = mb1[t];
    for (int i = 0; i < 256; ++i) acc = fmaf(merged[i], mW1[i * 128 + t], acc);
    acc = (acc - m_m[t]) * rsqrtf(m_v[t] + BN_EPS) * m_g[t] + m_b[t];
    h[t] = acc > 0.f ? acc : 0.f;
    __syncthreads();
    float acc2 = mb2[t];
    for (int k = 0; k < 128; ++k) acc2 = fmaf(h[k], mW2[k * 128 + t], acc2);
    sea[t] = acc2;
    __syncthreads();
    float aq = qb[t], ak = kb[t];
    for (int k = 0; k < 128; ++k) {
        const float e = sea[k];
        aq = fmaf(e, qW[k * 128 + t], aq);
        ak = fmaf(e, kW[k * 128 + t], ak);
    }
    eaq[t] = aq;
    eak[t] = ak;
}

// ---------------------------------------------------------------- tile GEMM core (x in LDS, W from L2)
__device__ __forceinline__ void tile_gemm(const float* __restrict__ T,
                                          const float* __restrict__ W,
                                          int i0, int j0, float acc[4][8])
{
    for (int k4 = 0; k4 < 32; ++k4) {
        float4 xr[4];
#pragma unroll
        for (int i = 0; i < 4; ++i)
            xr[i] = *(const float4*)(T + (i0 + i) * LDS_STRIDE + k4 * 4);
#pragma unroll
        for (int kk = 0; kk < 4; ++kk) {
            const float* wr = W + (size_t)(k4 * 4 + kk) * 128 + j0;
            const float4 w0 = *(const float4*)(wr);
            const float4 w1 = *(const float4*)(wr + 4);
#pragma unroll
            for (int i = 0; i < 4; ++i) {
                const float xv = ((const float*)&xr[i])[kk];
                acc[i][0] = fmaf(xv, w0.x, acc[i][0]);
                acc[i][1] = fmaf(xv, w0.y, acc[i][1]);
                acc[i][2] = fmaf(xv, w0.z, acc[i][2]);
                acc[i][3] = fmaf(xv, w0.w, acc[i][3]);
                acc[i][4] = fmaf(xv, w1.x, acc[i][4]);
                acc[i][5] = fmaf(xv, w1.y, acc[i][5]);
                acc[i][6] = fmaf(xv, w1.z, acc[i][6]);
                acc[i][7] = fmaf(xv, w1.w, acc[i][7]);
            }
        }
    }
}

// ---------------------------------------------------------------- Q/K/V: W in LDS, x streamed via L1
// blockIdx.y selects the weight matrix. 64 KB LDS -> 2 blocks/CU, but the
// k-loop has NO barriers and no L2-latency dependence: x loads are streaming
// (L1-resident, independent addresses), W reads come from LDS.
__global__ __launch_bounds__(256) void k_qkv(
    const float* __restrict__ x,
    const float* __restrict__ qW, const float* __restrict__ eaq,
    const float* __restrict__ kW, const float* __restrict__ eak,
    const float* __restrict__ vW, const float* __restrict__ vb,
    float* __restrict__ Q, float* __restrict__ K, float* __restrict__ V, int N)
{
    __shared__ float sw[128 * 128];   // one full weight matrix
    const int tid = threadIdx.x;
    const int w   = blockIdx.y;
    const float* W  = (w == 0) ? qW  : (w == 1) ? kW  : vW;
    const float* bi = (w == 0) ? eaq : (w == 1) ? eak : vb;  // eaq/eak fold ea-term + bias
    float* O        = (w == 0) ? Q   : (w == 1) ? K   : V;
    const float scale = (w == 0) ? 0.25f : 1.0f;             // q = (..)/sqrt(16)

    // stage W -> LDS (once per block; 4096 float4, 16 per thread)
    {
        const float4* Wv = (const float4*)W;
        float4* swv = (float4*)sw;
#pragma unroll
        for (int r = 0; r < 16; ++r) swv[r * 256 + tid] = Wv[r * 256 + tid];
    }
    __syncthreads();

    const int n0 = blockIdx.x * TM;
    const int tj = tid & 15, ti = tid >> 4;   // ti 0..15 -> 4 rows each
    const int j0 = tj * 8;
    const int r0 = n0 + ti * 4;

    // clamp row pointers (OOB rows compute garbage, stores are guarded)
    const float* rp[4];
#pragma unroll
    for (int i = 0; i < 4; ++i) {
        const int n = r0 + i;
        rp[i] = x + (size_t)(n < N ? n : N - 1) * 128;
    }

    float acc[4][8] = {};
#pragma unroll 2
    for (int k4 = 0; k4 < 32; ++k4) {
        float4 xr[4];
#pragma unroll
        for (int i = 0; i < 4; ++i)
            xr[i] = *(const float4*)(rp[i] + k4 * 4);
#pragma unroll
        for (int kk = 0; kk < 4; ++kk) {
            const float* wr = sw + (k4 * 4 + kk) * 128 + j0;
            const float4 w0 = *(const float4*)(wr);
            const float4 w1 = *(const float4*)(wr + 4);
#pragma unroll
            for (int i = 0; i < 4; ++i) {
                const float xv = ((const float*)&xr[i])[kk];
                acc[i][0] = fmaf(xv, w0.x, acc[i][0]);
                acc[i][1] = fmaf(xv, w0.y, acc[i][1]);
                acc[i][2] = fmaf(xv, w0.z, acc[i][2]);
                acc[i][3] = fmaf(xv, w0.w, acc[i][3]);
                acc[i][4] = fmaf(xv, w1.x, acc[i][4]);
                acc[i][5] = fmaf(xv, w1.y, acc[i][5]);
                acc[i][6] = fmaf(xv, w1.z, acc[i][6]);
                acc[i][7] = fmaf(xv, w1.w, acc[i][7]);
            }
        }
    }

    const float4 b0 = *(const float4*)(bi + j0);
    const float4 b1 = *(const float4*)(bi + j0 + 4);
#pragma unroll
    for (int i = 0; i < 4; ++i) {
        const int n = r0 + i;
        if (n >= N) continue;
        float4 o0, o1;
        o0.x = (acc[i][0] + b0.x) * scale; o0.y = (acc[i][1] + b0.y) * scale;
        o0.z = (acc[i][2] + b0.z) * scale; o0.w = (acc[i][3] + b0.w) * scale;
        o1.x = (acc[i][4] + b1.x) * scale; o1.y = (acc[i][5] + b1.y) * scale;
        o1.z = (acc[i][6] + b1.z) * scale; o1.w = (acc[i][7] + b1.w) * scale;
        *(float4*)(O + (size_t)n * 128 + j0)     = o0;
        *(float4*)(O + (size_t)n * 128 + j0 + 4) = o1;
    }
}

// ---------------------------------------------------------------- edge pass 1: ex + ssum
__global__ __launch_bounds__(256) void k_edge1(
    const int* __restrict__ ei, const float* __restrict__ Q,
    const float* __restrict__ K, float* __restrict__ ex,
    float* __restrict__ ssum, int E)
{
    const int t = blockIdx.x * 256 + threadIdx.x;   // one (edge, head) per thread
    const int e = t >> 3;
    if (e >= E) return;
    const int h = t & 7;
    const int s = ei[e];
    const int d = ei[E + e];
    const float* qp = Q + (size_t)s * 128 + h * 16;
    const float* kp = K + (size_t)d * 128 + h * 16;
    float acc = 0.f;
#pragma unroll
    for (int r = 0; r < 4; ++r) {
        const float4 a = *(const float4*)(qp + r * 4);
        const float4 b = *(const float4*)(kp + r * 4);
        acc += a.x * b.x + a.y * b.y + a.z * b.z + a.w * b.w;
    }
    const float v = __expf(acc);   // |score| small; no max-subtraction needed
    ex[(size_t)e * 8 + h] = v;
    unsafeAtomicAdd(&ssum[(size_t)s * 8 + h], v);
}

// ---------------------------------------------------------------- CSR build (dst)
__global__ __launch_bounds__(256) void k_hist(const int* __restrict__ ei,
                                              int* __restrict__ deg, int E)
{
    const int e = blockIdx.x * 256 + threadIdx.x;
    if (e < E) atomicAdd(&deg[ei[E + e]], 1);
}

__global__ __launch_bounds__(256) void k_scan_partial(const int* __restrict__ deg,
                                                      int* __restrict__ part, int N)
{
    __shared__ int sd[256];
    const int b = blockIdx.x, t = threadIdx.x;
    const int base = b * SCAN_CHUNK + t * 4;
    int s = 0;
#pragma unroll
    for (int i = 0; i < 4; ++i) { const int idx = base + i; if (idx < N) s += deg[idx]; }
    sd[t] = s; __syncthreads();
    for (int off = 128; off > 0; off >>= 1) {
        if (t < off) sd[t] += sd[t + off];
        __syncthreads();
    }
    if (t == 0) part[b] = sd[0];
}

__global__ __launch_bounds__(256) void k_scan_top(int* __restrict__ part, int nb)
{
    __shared__ int sd[256];
    const int t = threadIdx.x;
    const int orig = (t < nb) ? part[t] : 0;
    sd[t] = orig;
    __syncthreads();
    for (int off = 1; off < 256; off <<= 1) {
        const int v = (t >= off) ? sd[t - off] : 0;
        __syncthreads();
        sd[t] += v;
        __syncthreads();
    }
    if (t < nb) part[t] = sd[t] - orig;   // exclusive
}

__global__ __launch_bounds__(256) void k_scan_final(const int* __restrict__ deg,
                                                    const int* __restrict__ part,
                                                    int* __restrict__ row_start,
                                                    int* __restrict__ cursor, int N)
{
    __shared__ int ts[256];
    const int b = blockIdx.x, t = threadIdx.x;
    const int base = b * SCAN_CHUNK + t * 4;
    int v[4]; int s = 0;
#pragma unroll
    for (int i = 0; i < 4; ++i) { const int idx = base + i; v[i] = (idx < N) ? deg[idx] : 0; s += v[i]; }
    ts[t] = s; __syncthreads();
    for (int off = 1; off < 256; off <<= 1) {
        const int vv = (t >= off) ? ts[t - off] : 0;
        __syncthreads();
        ts[t] += vv;
        __syncthreads();
    }
    int run = part[b] + ((t > 0) ? ts[t - 1] : 0);
#pragma unroll
    for (int i = 0; i < 4; ++i) {
        const int idx = base + i;
        if (idx < N) { row_start[idx] = run; cursor[idx] = run; run += v[i]; }
    }
}

__global__ __launch_bounds__(256) void k_scatter(const int* __restrict__ ei,
                                                 int* __restrict__ cursor,
                                                 int* __restrict__ elist, int E)
{
    const int e = blockIdx.x * 256 + threadIdx.x;
    if (e < E) {
        const int pos = atomicAdd(&cursor[ei[E + e]], 1);
        elist[pos] = e;
    }
}

// ---------------------------------------------------------------- aggregation: 1 wave / dst node
__global__ __launch_bounds__(256) void k_aggr(
    const int* __restrict__ ei, const int* __restrict__ elist,
    const int* __restrict__ row_start, const int* __restrict__ deg,
    const float* __restrict__ V, const float* __restrict__ ex,
    const float* __restrict__ ssum, float* __restrict__ aggr, int N, int E)
{
    const int tid = threadIdx.x;
    const int n = blockIdx.x * 4 + (tid >> 6);
    if (n >= N) return;
    const int lane = tid & 63;
    const int h = lane >> 3;
    const int rs = row_start[n];
    const int dg = deg[n];
    float2 acc = make_float2(0.f, 0.f);
    for (int j = 0; j < dg; ++j) {
        const int e = elist[rs + j];
        const int s = ei[e];
        const float a = ex[(size_t)e * 8 + h] / ssum[(size_t)s * 8 + h];
        const float2 v = *(const float2*)(V + (size_t)s * 128 + lane * 2);
        acc.x = fmaf(v.x, a, acc.x);
        acc.y = fmaf(v.y, a, acc.y);
    }
    *(float2*)(aggr + (size_t)n * 128 + lane * 2) = acc;
}

// ---------------------------------------------------------------- fused residual + out MLP (round-3 proven)
__global__ __launch_bounds__(256, 4) void k_out(
    const float* __restrict__ x, const float* __restrict__ aggr,
    const float* __restrict__ resW,
    const float* __restrict__ oW1, const float* __restrict__ ob1,
    const float* __restrict__ o_g, const float* __restrict__ o_b,
    const float* __restrict__ o_m, const float* __restrict__ o_v,
    const float* __restrict__ oW2, const float* __restrict__ ob2,
    float* __restrict__ out, int N)
{
    __shared__ float sa[TM * LDS_STRIDE];
    const int tid = threadIdx.x;
    const int n0 = blockIdx.x * TM;
#pragma unroll
    for (int r = 0; r < 8; ++r) {
        const int flat = (r * 256 + tid) * 4;
        const int i = flat >> 7, c = flat & 127;
        const int n = n0 + i;
        float4 xv = make_float4(0.f, 0.f, 0.f, 0.f);
        if (n < N) xv = *(const float4*)(x + (size_t)n * 128 + c);
        float* p = sa + i * LDS_STRIDE + c;
        p[0] = xv.x; p[1] = xv.y; p[2] = xv.z; p[3] = xv.w;
    }
    __syncthreads();
    const int tj = tid & 15, ti = tid >> 4;
    const int j0 = tj * 8, i0 = ti * 4;

    // stage 1: z = x @ resW + aggr  (z stays in registers across the sync)
    float z[4][8] = {};
    tile_gemm(sa, resW, i0, j0, z);
#pragma unroll
    for (int i = 0; i < 4; ++i) {
        const int n = n0 + i0 + i;
        float4 a0 = make_float4(0.f, 0.f, 0.f, 0.f), a1 = a0;
        if (n < N) {
            a0 = *(const float4*)(aggr + (size_t)n * 128 + j0);
            a1 = *(const float4*)(aggr + (size_t)n * 128 + j0 + 4);
        }
        z[i][0] += a0.x; z[i][1] += a0.y; z[i][2] += a0.z; z[i][3] += a0.w;
        z[i][4] += a1.x; z[i][5] += a1.y; z[i][6] += a1.z; z[i][7] += a1.w;
    }
    __syncthreads();   // all reads of x-tile done
#pragma unroll
    for (int i = 0; i < 4; ++i) {
        float* p = sa + (i0 + i) * LDS_STRIDE + j0;
#pragma unroll
        for (int j = 0; j < 8; ++j) p[j] = z[i][j];
    }
    __syncthreads();

    // stage 2: t = leaky_relu(bn(z @ oW1 + ob1))
    {
        float acc[4][8] = {};
        tile_gemm(sa, oW1, i0, j0, acc);
        const float4 bb0 = *(const float4*)(ob1 + j0), bb1 = *(const float4*)(ob1 + j0 + 4);
        const float4 mm0 = *(const float4*)(o_m + j0), mm1 = *(const float4*)(o_m + j0 + 4);
        const float4 vv0 = *(const float4*)(o_v + j0), vv1 = *(const float4*)(o_v + j0 + 4);
        const float4 gg0 = *(const float4*)(o_g + j0), gg1 = *(const float4*)(o_g + j0 + 4);
        const float4 oo0 = *(const float4*)(o_b + j0), oo1 = *(const float4*)(o_b + j0 + 4);
        float bbv[8] = {bb0.x, bb0.y, bb0.z, bb0.w, bb1.x, bb1.y, bb1.z, bb1.w};
        float mmv[8] = {mm0.x, mm0.y, mm0.z, mm0.w, mm1.x, mm1.y, mm1.z, mm1.w};
        float vvv[8] = {vv0.x, vv0.y, vv0.z, vv0.w, vv1.x, vv1.y, vv1.z, vv1.w};
        float ggv[8] = {gg0.x, gg0.y, gg0.z, gg0.w, gg1.x, gg1.y, gg1.z, gg1.w};
        float oov[8] = {oo0.x, oo0.y, oo0.z, oo0.w, oo1.x, oo1.y, oo1.z, oo1.w};
#pragma unroll
        for (int i = 0; i < 4; ++i)
#pragma unroll
            for (int j = 0; j < 8; ++j) {
                float u = acc[i][j] + bbv[j];
                u = (u - mmv[j]) * rsqrtf(vvv[j] + BN_EPS) * ggv[j] + oov[j];
                acc[i][j] = u > 0.f ? u : 0.01f * u;   // leaky_relu(0.01)
            }
        __syncthreads();   // all reads of z-tile done
#pragma unroll
        for (int i = 0; i < 4; ++i) {
            float* p = sa + (i0 + i) * LDS_STRIDE + j0;
#pragma unroll
            for (int j = 0; j < 8; ++j) p[j] = acc[i][j];
        }
    }
    __syncthreads();

    // stage 3: out = t @ oW2 + ob2
    {
        float acc[4][8] = {};
        tile_gemm(sa, oW2, i0, j0, acc);
        const float4 b0 = *(const float4*)(ob2 + j0);
        const float4 b1 = *(const float4*)(ob2 + j0 + 4);
#pragma unroll
        for (int i = 0; i < 4; ++i) {
            const int n = n0 + i0 + i;
            if (n >= N) continue;
            float4 o0, o1;
            o0.x = acc[i][0] + b0.x; o0.y = acc[i][1] + b0.y;
            o0.z = acc[i][2] + b0.z; o0.w = acc[i][3] + b0.w;
            o1.x = acc[i][4] + b1.x; o1.y = acc[i][5] + b1.y;
            o1.z = acc[i][6] + b1.z; o1.w = acc[i][7] + b1.w;
            *(float4*)(out + (size_t)n * 128 + j0)     = o0;
            *(float4*)(out + (size_t)n * 128 + j0 + 4) = o1;
        }
    }
}

// ---------------------------------------------------------------- launch
extern "C" void kernel_launch(void* const* d_in, const int* in_sizes, int n_in,
                              void* d_out, int out_size, void* d_ws, size_t ws_size,
                              hipStream_t stream)
{
    const float* x    = (const float*)d_in[0];
    const int*   ei   = (const int*)d_in[1];
    const float* nt   = (const float*)d_in[2];
    const float* et   = (const float*)d_in[3];
    const float* mW1  = (const float*)d_in[4];
    const float* mb1  = (const float*)d_in[5];
    const float* m_g  = (const float*)d_in[6];
    const float* m_b  = (const float*)d_in[7];
    const float* m_m  = (const float*)d_in[8];
    const float* m_v  = (const float*)d_in[9];
    const float* mW2  = (const float*)d_in[10];
    const float* mb2  = (const float*)d_in[11];
    const float* resW = (const float*)d_in[12];
    const float* qW   = (const float*)d_in[13];
    const float* qb   = (const float*)d_in[14];
    const float* kW   = (const float*)d_in[15];
    const float* kb   = (const float*)d_in[16];
    const float* vW   = (const float*)d_in[17];
    const float* vb   = (const float*)d_in[18];
    const float* oW1  = (const float*)d_in[19];
    const float* ob1  = (const float*)d_in[20];
    const float* o_g  = (const float*)d_in[21];
    const float* o_b  = (const float*)d_in[22];
    const float* o_m  = (const float*)d_in[23];
    const float* o_v  = (const float*)d_in[24];
    const float* oW2  = (const float*)d_in[25];
    const float* ob2  = (const float*)d_in[26];
    float* out = (float*)d_out;

    const int N = in_sizes[0] / 128;
    const int E = in_sizes[1] / 2;

    // workspace layout (floats): eaq|eak | Q | K | V | ex | ssum | [ints] deg,row_start,cursor,part,elist
    float* ws   = (float*)d_ws;
    float* eaq  = ws;
    float* eak  = ws + 128;
    float* Q    = ws + 256;
    float* K    = Q + (size_t)N * 128;
    float* V    = K + (size_t)N * 128;
    float* ex   = V + (size_t)N * 128;
    float* ssum = ex + (size_t)E * 8;
    int* deg       = (int*)(ssum + (size_t)N * 8);
    int* row_start = deg + N;
    int* cursor    = row_start + N;
    int* part      = cursor + N;
    int* elist     = part + 256;
    float* aggr = Q;   // Q dead after edge pass 1

    const int nb   = (N + TM - 1) / TM;
    const int nbsc = (N + SCAN_CHUNK - 1) / SCAN_CHUNK;   // scan blocks (<=256)

    hipMemsetAsync(ssum, 0, (size_t)N * 8 * sizeof(float), stream);
    hipMemsetAsync(deg, 0, (size_t)N * sizeof(int), stream);

    k_ea<<<1, 128, 0, stream>>>(nt, et, mW1, mb1, m_g, m_b, m_m, m_v, mW2, mb2,
                                qW, qb, kW, kb, eaq, eak);
    k_qkv<<<dim3(nb, 3), 256, 0, stream>>>(x, qW, eaq, kW, eak, vW, vb, Q, K, V, N);

    // CSR build (independent of Q/K/V values)
    k_hist<<<(E + 255) / 256, 256, 0, stream>>>(ei, deg, E);
    k_scan_partial<<<nbsc, 256, 0, stream>>>(deg, part, N);
    k_scan_top<<<1, 256, 0, stream>>>(part, nbsc);
    k_scan_final<<<nbsc, 256, 0, stream>>>(deg, part, row_start, cursor, N);
    k_scatter<<<(E + 255) / 256, 256, 0, stream>>>(ei, cursor, elist, E);

    k_edge1<<<(int)(((size_t)E * 8 + 255) / 256), 256, 0, stream>>>(ei, Q, K, ex, ssum, E);
    k_aggr<<<(N + 3) / 4, 256, 0, stream>>>(ei, elist, row_start, deg, V, ex, ssum, aggr, N, E);
    k_out<<<nb, 256, 0, stream>>>(x, aggr, resW, oW1, ob1, o_g, o_b, o_m, o_v, oW2, ob2, out, N);
}